// Round 7
// baseline (11826.321 us; speedup 1.0000x reference)
//
#include <hip/hip_runtime.h>
#include <hip/hip_bf16.h>
#include <hip/hip_fp16.h>
#include <math.h>

#define BB 256
#define TT 256
// H=[128,32,32], TH=192, ZDIM=64, ATT=4

__device__ __forceinline__ float sigf(float x) { return 1.f / (1.f + expf(-x)); }

// lgkm-only barrier: drains LDS ops; global loads may stay in flight.
#define BAR() do {                                   \
    __atomic_signal_fence(__ATOMIC_SEQ_CST);         \
    __builtin_amdgcn_s_waitcnt(0xC07F);              \
    __builtin_amdgcn_s_barrier();                    \
    __atomic_signal_fence(__ATOMIC_SEQ_CST);         \
} while (0)

using hf2 = __attribute__((ext_vector_type(2))) _Float16;

__device__ __forceinline__ float fdot2f(hf2 a, hf2 b, float c) {
#if __has_builtin(__builtin_amdgcn_fdot2)
    return __builtin_amdgcn_fdot2(a, b, c, false);
#else
    return c + (float)a[0] * (float)b[0] + (float)a[1] * (float)b[1];
#endif
}

// Packed-pair GEMV slice: KP kpairs, 4 output cols.
// Weight layout: row = kpair, 2N halves/row; (kp, c) pair at [kp*2N + 2c].
// One float4 = 4 cols x 2 ks. aH = fp16 activation base (even k offset).
template <int KP>
__device__ __forceinline__ void pdot4(const __half* __restrict__ WB, int rowHalves,
                                      const __half* __restrict__ aH, float acc[4]) {
#pragma unroll
    for (int kp = 0; kp < KP; ++kp) {
        const float4 wv = *(const float4*)(WB + (size_t)kp * rowHalves);
        const hf2* w2 = (const hf2*)&wv;
        const hf2 a2 = *(const hf2*)(aH + 2 * kp);
        acc[0] = fdot2f(a2, w2[0], acc[0]);
        acc[1] = fdot2f(a2, w2[1], acc[1]);
        acc[2] = fdot2f(a2, w2[2], acc[2]);
        acc[3] = fdot2f(a2, w2[3], acc[3]);
    }
}

// fp32 [K][N] -> fp16 kpair-interleaved: dst[kp*2N + 2c + o] = src[(2kp+o)*N + c]
__global__ void f2hpk(const float* __restrict__ s, __half* __restrict__ d, int K, int N) {
    int i = blockIdx.x * 256 + threadIdx.x;
    if (i < K * N) {
        int kp = i / (2 * N);
        int r  = i - kp * 2 * N;
        int c  = r >> 1;
        int o  = r & 1;
        d[i] = __float2half(s[(size_t)(2 * kp + o) * N + c]);
    }
}

// ---------------------------------------------------------------------------
// Kernel 1: G = X @ W + bias
// ---------------------------------------------------------------------------
#define GT_M 128
#define GT_N 64
#define GT_K 16

__device__ __forceinline__ void stvec4(float* p, float4 v) { *(float4*)p = v; }
__device__ __forceinline__ void stvec4(__half* p, float4 v) {
    *(__half2*)p = __floats2half2_rn(v.x, v.y);
    *(__half2*)(p + 2) = __floats2half2_rn(v.z, v.w);
}

template <typename OT>
__global__ __launch_bounds__(256)
void xw_gemm(const float* __restrict__ X, const float* __restrict__ W,
             const float* __restrict__ bias, OT* __restrict__ G,
             int M, int N, int K) {
    __shared__ float As[GT_K][GT_M + 4];
    __shared__ float Bs[GT_K][GT_N];
    const int tid = threadIdx.x;
    const int bm = blockIdx.y * GT_M;
    const int bn = blockIdx.x * GT_N;
    const int tx = tid & 15;
    const int ty = tid >> 4;

    float acc[8][4];
#pragma unroll
    for (int i = 0; i < 8; ++i)
#pragma unroll
        for (int j = 0; j < 4; ++j) acc[i][j] = 0.f;

    for (int kt = 0; kt < K; kt += GT_K) {
#pragma unroll
        for (int i = 0; i < 8; ++i) {
            int idx = i * 256 + tid;
            int m = idx >> 4, k = idx & 15;
            int gk = kt + k;
            As[k][m] = (gk < K) ? X[(size_t)(bm + m) * K + gk] : 0.f;
        }
#pragma unroll
        for (int i = 0; i < 4; ++i) {
            int idx = i * 256 + tid;
            int k = idx >> 6, n = idx & 63;
            int gk = kt + k;
            Bs[k][n] = (gk < K) ? W[(size_t)gk * N + bn + n] : 0.f;
        }
        __syncthreads();
#pragma unroll
        for (int k = 0; k < GT_K; ++k) {
            float a[8], b[4];
            const float4 a0 = *(const float4*)&As[k][ty * 8];
            const float4 a1 = *(const float4*)&As[k][ty * 8 + 4];
            const float4 bv = *(const float4*)&Bs[k][tx * 4];
            a[0]=a0.x; a[1]=a0.y; a[2]=a0.z; a[3]=a0.w;
            a[4]=a1.x; a[5]=a1.y; a[6]=a1.z; a[7]=a1.w;
            b[0]=bv.x; b[1]=bv.y; b[2]=bv.z; b[3]=bv.w;
#pragma unroll
            for (int i = 0; i < 8; ++i)
#pragma unroll
                for (int j = 0; j < 4; ++j) acc[i][j] += a[i] * b[j];
        }
        __syncthreads();
    }
    const int n0 = bn + tx * 4;
#pragma unroll
    for (int i = 0; i < 8; ++i) {
        int m = bm + ty * 8 + i;
        float4 v;
        v.x = acc[i][0] + bias[n0 + 0];
        v.y = acc[i][1] + bias[n0 + 1];
        v.z = acc[i][2] + bias[n0 + 2];
        v.w = acc[i][3] + bias[n0 + 3];
        stvec4(&G[(size_t)m * N + n0], v);
    }
}

// ---------------------------------------------------------------------------
// Kernel 2: persistent recurrence. 256 blocks x 1024 threads (16 waves/CU),
// kpair-packed fp16 weights + v_dot2_f32_f16, lgkm-only barriers.
// ---------------------------------------------------------------------------
__global__ __launch_bounds__(1024)
void marn_rec(const float* __restrict__ G0, const __half* __restrict__ G1h,
              const __half* __restrict__ G2h,
              const __half* __restrict__ pU0, const __half* __restrict__ pV0,
              const __half* __restrict__ pU1, const __half* __restrict__ pV1,
              const __half* __restrict__ pU2, const __half* __restrict__ pV2,
              const __half* __restrict__ paw1, const float* __restrict__ ab1,
              const __half* __restrict__ paw2, const float* __restrict__ ab2,
              const __half* __restrict__ pcw10, const float* __restrict__ cb10,
              const float* __restrict__ cw20, const float* __restrict__ cb20,
              const __half* __restrict__ pcw11, const float* __restrict__ cb11,
              const float* __restrict__ cw21, const float* __restrict__ cb21,
              const __half* __restrict__ pcw12, const float* __restrict__ cb12,
              const float* __restrict__ cw22, const float* __restrict__ cb22,
              const float* __restrict__ fw1, const float* __restrict__ fb1,
              const float* __restrict__ fw2, const float* __restrict__ fb2,
              float* __restrict__ out) {
    __shared__ float hz[256];                        // [h0|h1|h2|z] fp32
    __shared__ __align__(4) __half hzH[256];         // fp16 mirror
    __shared__ float cst[192];
    __shared__ __align__(4) __half a1sH[256];
    __shared__ float attE[768];
    __shared__ float hid[128];
    __shared__ float rinv[4];
    __shared__ float scratch[3840];
    __shared__ float c2w[3072];   // cw20(2048)|cw21(512)|cw22(512)

    const int tid = threadIdx.x;
    const int row = blockIdx.x;

    if (tid < 256) { hz[tid] = 0.f; hzH[tid] = __float2half(0.f); }
    else if (tid < 448) cst[tid - 256] = 0.f;
    for (int i = tid; i < 2048; i += 1024) c2w[i] = cw20[i];
    if (tid < 512) c2w[2048 + tid] = cw21[tid];
    else c2w[2560 + (tid - 512)] = cw22[tid - 512];
    __syncthreads();

    // ---- stage A mapping (960 active): 16-kpair chunks ----
    const __half* WBa = nullptr; int ROWa = 0, HOa = 0, SOa = 0;
    if (tid < 768) {
        const int g = tid & 127, kc = tid >> 7;      // 128 col-groups, kc 0..5
        ROWa = 1024;                                  // 2N, N=512
        if (kc < 4) { WBa = pU0 + (size_t)(16 * kc) * 1024 + g * 8; HOa = 32 * kc; }
        else        { WBa = pV0 + (size_t)(16 * (kc - 4)) * 1024 + g * 8; HOa = 192 + 32 * (kc - 4); }
        SOa = kc * 512 + g * 4;
    } else if (tid < 960) {
        const int u = tid - 768;                      // 0..191
        const int kc = u / 64, r = u & 63;
        const int cell = r >> 5, g = r & 31;          // 32 col-groups per cell
        const __half* Uc = cell ? pU2 : pU1;
        const __half* Vc = cell ? pV2 : pV1;
        ROWa = 256;                                   // 2N, N=128
        if (kc == 0)      { WBa = Uc + g * 8;                       HOa = 128 + 32 * cell; }
        else if (kc == 1) { WBa = Vc + g * 8;                       HOa = 192; }
        else              { WBa = Vc + (size_t)16 * 256 + g * 8;    HOa = 224; }
        SOa = 3072 + kc * 256 + cell * 128 + g * 4;
    }
    // ---- att1 mapping (512 active): 12-kpair chunks ----
    const __half* WB1 = nullptr; int HO1 = 0, SO1 = 0;
    if (tid < 512) {
        const int g = tid & 63, kc = tid >> 6;       // 64 groups, kc 0..7
        WB1 = paw1 + (size_t)(12 * kc) * 512 + g * 8;
        HO1 = 24 * kc;
        SO1 = kc * 256 + g * 4;
    }
    // ---- att2 mapping (768 active): 32-kpair chunks ----
    const int kc2 = tid / 192;                       // 0..3 (and junk for >=768)
    const int g2a = tid - kc2 * 192;
    const __half* WB2 = paw2 + (size_t)(32 * (kc2 & 3)) * 1536 + g2a * 8;
    const int HO2 = 64 * (kc2 & 3);
    const int SO2 = (kc2 & 3) * 768 + g2a * 4;
    // ---- comp1 mapping (384 active) ----
    const __half* WBc = nullptr; int ROWc = 0, HOc = 0, SOc = 0, HSELo = 0, HSELm = 0;
    if (tid < 256) {
        const int g = tid & 15, kc = tid >> 4;       // 16 groups, kc 0..15
        WBc = pcw10 + (size_t)(16 * kc) * 128 + g * 8;
        ROWc = 128;
        HOc = 32 * kc;
        SOc = kc * 64 + g * 4;
        HSELo = 0; HSELm = 127;
    } else if (tid < 384) {
        const int u = tid - 256;                      // 0..127
        const int cell = u >> 6, r = u & 63;
        const int kc = r >> 3, g = r & 7;             // 8 groups, kc 0..7
        WBc = (cell ? pcw12 : pcw11) + (size_t)(8 * kc) * 64 + g * 8;
        ROWc = 64;
        HOc = 512 + 128 * cell + 16 * kc;
        SOc = 1024 + cell * 256 + kc * 32 + g * 4;
        HSELo = 128 + 32 * cell; HSELm = 31;
    }
    const int AHc = HOc / 192;
    const int HBc = (tid < 256) ? 0 : (512 + 128 * (((tid - 256) >> 6) & 1));
    // ---- gates / G-prefetch mapping (192 active) ----
    const int g12_cell = ((tid - 128) >> 5) & 1;
    const int g12_uu   = (tid - 128) & 31;

    float  g0p[4];
    __half g12p[4];
    if (tid < 128) {
        const float* gp = G0 + ((size_t)row * TT + 0) * 512;
#pragma unroll
        for (int q = 0; q < 4; ++q) g0p[q] = gp[q * 128 + tid];
    } else if (tid < 192) {
        const __half* gp = (g12_cell ? G2h : G1h) + ((size_t)row * TT + 0) * 128;
#pragma unroll
        for (int q = 0; q < 4; ++q) g12p[q] = gp[q * 32 + g12_uu];
    }

    for (int t = 0; t < TT; ++t) {
        // ======== stage A compute ========
        if (tid < 960) {
            float acc[4] = {0.f, 0.f, 0.f, 0.f};
            pdot4<16>(WBa, ROWa, &hzH[HOa], acc);
            *(float4*)&scratch[SOa] = make_float4(acc[0], acc[1], acc[2], acc[3]);
        }
        BAR();
        // ======== gates (+ G prefetch for t+1 right after consumption) ====
        if (tid < 128) {
            float s[4];
#pragma unroll
            for (int q = 0; q < 4; ++q) {
                const int c4 = q * 128 + tid;
                float v = g0p[q];
#pragma unroll
                for (int kc = 0; kc < 6; ++kc) v += scratch[kc * 512 + c4];
                s[q] = v;
            }
            const float f  = sigf(s[0]);
            const float ig = sigf(s[1]);
            const float o  = sigf(s[2]);
            const float ch = tanhf(s[3]);
            const float c = f * cst[tid] + ig * ch;
            cst[tid] = c;
            const float h = tanhf(c) * o;
            hz[tid] = h;
            hzH[tid] = __float2half(h);
            const int tn = (t + 1 < TT) ? t + 1 : TT - 1;
            const float* gp = G0 + ((size_t)row * TT + tn) * 512;
#pragma unroll
            for (int q = 0; q < 4; ++q) g0p[q] = gp[q * 128 + tid];
        } else if (tid < 192) {
            const int cell = g12_cell, uu = g12_uu;
            float s[4];
#pragma unroll
            for (int q = 0; q < 4; ++q) {
                float v = __half2float(g12p[q]);
#pragma unroll
                for (int kc = 0; kc < 3; ++kc)
                    v += scratch[3072 + kc * 256 + cell * 128 + q * 32 + uu];
                s[q] = v;
            }
            const float f  = sigf(s[0]);
            const float ig = sigf(s[1]);
            const float o  = sigf(s[2]);
            const float ch = tanhf(s[3]);
            const int si = 128 + 32 * cell + uu;
            const float c = f * cst[si] + ig * ch;
            cst[si] = c;
            const float h = tanhf(c) * o;
            hz[si] = h;
            hzH[si] = __float2half(h);
            const int tn = (t + 1 < TT) ? t + 1 : TT - 1;
            const __half* gp = (cell ? G2h : G1h) + ((size_t)row * TT + tn) * 128;
#pragma unroll
            for (int q = 0; q < 4; ++q) g12p[q] = gp[q * 32 + uu];
        }
        BAR();
        // ======== att1 compute ========
        if (tid < 512) {
            float acc[4] = {0.f, 0.f, 0.f, 0.f};
            pdot4<12>(WB1, 512, &hzH[HO1], acc);
            *(float4*)&scratch[SO1] = make_float4(acc[0], acc[1], acc[2], acc[3]);
        }
        BAR();
        // ======== att1 reduce + relu ========
        if (tid < 256) {
            float s = ab1[tid];
#pragma unroll
            for (int kc = 0; kc < 8; ++kc) s += scratch[kc * 256 + tid];
            a1sH[tid] = __float2half(fmaxf(s, 0.f));
        }
        BAR();
        // ======== att2 compute ========
        if (tid < 768) {
            float acc[4] = {0.f, 0.f, 0.f, 0.f};
            pdot4<16>(WB2, 1536, &a1sH[HO2], acc);
            pdot4<16>(WB2 + (size_t)16 * 1536, 1536, &a1sH[HO2 + 32], acc);
            *(float4*)&scratch[SO2] = make_float4(acc[0], acc[1], acc[2], acc[3]);
        }
        BAR();
        // ======== att2 reduce + sigmoid + exp ========
        if (tid < 768) {
            float s = ab2[tid];
#pragma unroll
            for (int kc = 0; kc < 4; ++kc) s += scratch[kc * 768 + tid];
            attE[tid] = expf(sigf(s));
        }
        BAR();
        // ======== softmax reciprocal denominators ========
        if (tid < 256) {
            const int a = tid >> 6, lane = tid & 63;
            float v = attE[a * 192 + lane] + attE[a * 192 + 64 + lane]
                    + attE[a * 192 + 128 + lane];
#pragma unroll
            for (int s = 32; s >= 1; s >>= 1) v += __shfl_xor(v, s);
            if (lane == 0) rinv[a] = 1.f / v;
        }
        BAR();
        // ======== comp1 compute (att_out fused) ========
        if (tid < 256) {
            const float ri = rinv[AHc];
            hf2 av2[16];
#pragma unroll
            for (int p = 0; p < 16; ++p) {
                const int i0 = HOc + 2 * p;
                const float a0 = attE[i0]     * ri * hz[HSELo + ((i0 - HBc) & HSELm)];
                const float a1 = attE[i0 + 1] * ri * hz[HSELo + ((i0 + 1 - HBc) & HSELm)];
                hf2 v; v[0] = (_Float16)a0; v[1] = (_Float16)a1;
                av2[p] = v;
            }
            float acc[4] = {0.f, 0.f, 0.f, 0.f};
#pragma unroll
            for (int kp = 0; kp < 16; ++kp) {
                const float4 wv = *(const float4*)(WBc + (size_t)kp * ROWc);
                const hf2* w2 = (const hf2*)&wv;
                acc[0] = fdot2f(av2[kp], w2[0], acc[0]);
                acc[1] = fdot2f(av2[kp], w2[1], acc[1]);
                acc[2] = fdot2f(av2[kp], w2[2], acc[2]);
                acc[3] = fdot2f(av2[kp], w2[3], acc[3]);
            }
            *(float4*)&scratch[SOc] = make_float4(acc[0], acc[1], acc[2], acc[3]);
        } else if (tid < 384) {
            const float ri = rinv[AHc];
            hf2 av2[8];
#pragma unroll
            for (int p = 0; p < 8; ++p) {
                const int i0 = HOc + 2 * p;
                const float a0 = attE[i0]     * ri * hz[HSELo + ((i0 - HBc) & HSELm)];
                const float a1 = attE[i0 + 1] * ri * hz[HSELo + ((i0 + 1 - HBc) & HSELm)];
                hf2 v; v[0] = (_Float16)a0; v[1] = (_Float16)a1;
                av2[p] = v;
            }
            float acc[4] = {0.f, 0.f, 0.f, 0.f};
#pragma unroll
            for (int kp = 0; kp < 8; ++kp) {
                const float4 wv = *(const float4*)(WBc + (size_t)kp * ROWc);
                const hf2* w2 = (const hf2*)&wv;
                acc[0] = fdot2f(av2[kp], w2[0], acc[0]);
                acc[1] = fdot2f(av2[kp], w2[1], acc[1]);
                acc[2] = fdot2f(av2[kp], w2[2], acc[2]);
                acc[3] = fdot2f(av2[kp], w2[3], acc[3]);
            }
            *(float4*)&scratch[SOc] = make_float4(acc[0], acc[1], acc[2], acc[3]);
        }
        BAR();
        // ======== comp1 reduce + relu ========
        if (tid < 128) {
            float s;
            if (tid < 64) {
                s = cb10[tid];
#pragma unroll
                for (int kc = 0; kc < 16; ++kc) s += scratch[kc * 64 + tid];
            } else {
                const int cc = tid - 64;
                const int cell = cc >> 5, j = cc & 31;
                s = (cell ? cb12 : cb11)[j];
#pragma unroll
                for (int kc = 0; kc < 8; ++kc)
                    s += scratch[1024 + cell * 256 + kc * 32 + j];
            }
            hid[tid] = fmaxf(s, 0.f);
        }
        BAR();
        // ======== comp2 + z softmax (one wave) ========
        if (tid < 64) {
            const int j = tid;
            float acc;
            if (j < 32) {
                acc = cb20[j];
#pragma unroll
                for (int k = 0; k < 64; ++k) acc += hid[k] * c2w[k * 32 + j];
            } else if (j < 48) {
                const int o = j - 32; acc = cb21[o];
#pragma unroll
                for (int k = 0; k < 32; ++k) acc += hid[64 + k] * c2w[2048 + k * 16 + o];
            } else {
                const int o = j - 48; acc = cb22[o];
#pragma unroll
                for (int k = 0; k < 32; ++k) acc += hid[96 + k] * c2w[2560 + k * 16 + o];
            }
            const float e = expf(sigf(acc));
            float v = e;
#pragma unroll
            for (int s = 32; s >= 1; s >>= 1) v += __shfl_xor(v, s);
            const float z = e / v;
            hz[192 + j] = z;
            hzH[192 + j] = __float2half(z);
        }
        BAR();
    }

    __syncthreads();
    // ======== final MLP ========
    if (tid < 64) {
        const int j = tid;
        float acc = fb1[j];
#pragma unroll 8
        for (int k = 0; k < 64; ++k)  acc += hz[192 + k] * fw1[k * 64 + j];
#pragma unroll 8
        for (int k = 0; k < 192; ++k) acc += hz[k] * fw1[(64 + k) * 64 + j];
        hid[j] = fmaxf(acc, 0.f);
    }
    __syncthreads();
    if (tid < 64) {
        float v = hid[tid] * fw2[tid];
#pragma unroll
        for (int s = 32; s >= 1; s >>= 1) v += __shfl_xor(v, s);
        if (tid == 0) out[row] = v + fb2[0];
    }
}

// ---------------------------------------------------------------------------
extern "C" void kernel_launch(void* const* d_in, const int* in_sizes, int n_in,
                              void* d_out, int out_size, void* d_ws, size_t ws_size,
                              hipStream_t stream) {
    const float* x0   = (const float*)d_in[0];
    const float* x1   = (const float*)d_in[1];
    const float* x2   = (const float*)d_in[2];
    const float* W0   = (const float*)d_in[3];
    const float* U0   = (const float*)d_in[4];
    const float* V0   = (const float*)d_in[5];
    const float* b0   = (const float*)d_in[6];
    const float* W1   = (const float*)d_in[7];
    const float* U1   = (const float*)d_in[8];
    const float* V1   = (const float*)d_in[9];
    const float* b1   = (const float*)d_in[10];
    const float* W2   = (const float*)d_in[11];
    const float* U2   = (const float*)d_in[12];
    const float* V2   = (const float*)d_in[13];
    const float* b2   = (const float*)d_in[14];
    const float* aw1  = (const float*)d_in[15];
    const float* ab1  = (const float*)d_in[16];
    const float* aw2  = (const float*)d_in[17];
    const float* ab2  = (const float*)d_in[18];
    const float* cw10 = (const float*)d_in[19];
    const float* cb10 = (const float*)d_in[20];
    const float* cw20 = (const float*)d_in[21];
    const float* cb20 = (const float*)d_in[22];
    const float* cw11 = (const float*)d_in[23];
    const float* cb11 = (const float*)d_in[24];
    const float* cw21 = (const float*)d_in[25];
    const float* cb21 = (const float*)d_in[26];
    const float* cw12 = (const float*)d_in[27];
    const float* cb12 = (const float*)d_in[28];
    const float* cw22 = (const float*)d_in[29];
    const float* cb22 = (const float*)d_in[30];
    const float* fw1  = (const float*)d_in[31];
    const float* fb1  = (const float*)d_in[32];
    const float* fw2  = (const float*)d_in[33];
    const float* fb2  = (const float*)d_in[34];
    float* out = (float*)d_out;

    const size_t M = (size_t)BB * TT;   // 65536

    float*  G0  = (float*)d_ws;                 // M*512 f32
    __half* G1h = (__half*)(G0 + M * 512);      // M*128 f16
    __half* G2h = G1h + M * 128;                // M*128 f16
    __half* pU0   = G2h + M * 128;   // 128*512
    __half* pV0   = pU0 + 65536;     //  64*512
    __half* pU1   = pV0 + 32768;     //  32*128
    __half* pV1   = pU1 + 4096;      //  64*128
    __half* pU2   = pV1 + 8192;      //  32*128
    __half* pV2   = pU2 + 4096;      //  64*128
    __half* paw1  = pV2 + 8192;      // 192*256
    __half* paw2  = paw1 + 49152;    // 256*768
    __half* pcw10 = paw2 + 196608;   // 512*64
    __half* pcw11 = pcw10 + 32768;   // 128*32
    __half* pcw12 = pcw11 + 4096;    // 128*32

    // kpair-packed fp16 weight conversions
    f2hpk<<<(65536 + 255) / 256, 256, 0, stream>>>(U0, pU0, 128, 512);
    f2hpk<<<(32768 + 255) / 256, 256, 0, stream>>>(V0, pV0, 64, 512);
    f2hpk<<<(4096 + 255) / 256, 256, 0, stream>>>(U1, pU1, 32, 128);
    f2hpk<<<(8192 + 255) / 256, 256, 0, stream>>>(V1, pV1, 64, 128);
    f2hpk<<<(4096 + 255) / 256, 256, 0, stream>>>(U2, pU2, 32, 128);
    f2hpk<<<(8192 + 255) / 256, 256, 0, stream>>>(V2, pV2, 64, 128);
    f2hpk<<<(49152 + 255) / 256, 256, 0, stream>>>(aw1, paw1, 192, 256);
    f2hpk<<<(196608 + 255) / 256, 256, 0, stream>>>(aw2, paw2, 256, 768);
    f2hpk<<<(32768 + 255) / 256, 256, 0, stream>>>(cw10, pcw10, 512, 64);
    f2hpk<<<(4096 + 255) / 256, 256, 0, stream>>>(cw11, pcw11, 128, 32);
    f2hpk<<<(4096 + 255) / 256, 256, 0, stream>>>(cw12, pcw12, 128, 32);

    xw_gemm<float><<<dim3(512 / GT_N, M / GT_M), 256, 0, stream>>>(x0, W0, b0, G0, (int)M, 512, 300);
    xw_gemm<__half><<<dim3(128 / GT_N, M / GT_M), 256, 0, stream>>>(x1, W1, b1, G1h, (int)M, 128, 74);
    xw_gemm<__half><<<dim3(128 / GT_N, M / GT_M), 256, 0, stream>>>(x2, W2, b2, G2h, (int)M, 128, 35);

    // 256 blocks x 1024 threads, 1 row/block
    marn_rec<<<256, 1024, 0, stream>>>(G0, G1h, G2h, pU0, pV0, pU1, pV1, pU2, pV2,
                                       paw1, ab1, paw2, ab2,
                                       pcw10, cb10, cw20, cb20,
                                       pcw11, cb11, cw21, cb21,
                                       pcw12, cb12, cw22, cb22,
                                       fw1, fb1, fw2, fb2, out);
}

// Round 8
// 7543.910 us; speedup vs baseline: 1.5677x; 1.5677x over previous
//
#include <hip/hip_runtime.h>
#include <hip/hip_bf16.h>
#include <hip/hip_fp16.h>
#include <math.h>

#define BB 256
#define TT 256
// H=[128,32,32], TH=192, ZDIM=64, ATT=4

__device__ __forceinline__ float sigf(float x) { return 1.f / (1.f + expf(-x)); }

// lgkm-only barrier: drains LDS ops; global loads may stay in flight.
#define BAR() do {                                   \
    __atomic_signal_fence(__ATOMIC_SEQ_CST);         \
    __builtin_amdgcn_s_waitcnt(0xC07F);              \
    __builtin_amdgcn_s_barrier();                    \
    __atomic_signal_fence(__ATOMIC_SEQ_CST);         \
} while (0)

__global__ void f2h(const float* __restrict__ s, __half* __restrict__ d, int n) {
    int i = blockIdx.x * 256 + threadIdx.x;
    if (i < n) d[i] = __float2half(s[i]);
}

// ---------------------------------------------------------------------------
// Kernel 1: G = X @ W + bias
// ---------------------------------------------------------------------------
#define GT_M 128
#define GT_N 64
#define GT_K 16

__device__ __forceinline__ void stvec4(float* p, float4 v) { *(float4*)p = v; }
__device__ __forceinline__ void stvec4(__half* p, float4 v) {
    *(__half2*)p = __floats2half2_rn(v.x, v.y);
    *(__half2*)(p + 2) = __floats2half2_rn(v.z, v.w);
}

template <typename OT>
__global__ __launch_bounds__(256)
void xw_gemm(const float* __restrict__ X, const float* __restrict__ W,
             const float* __restrict__ bias, OT* __restrict__ G,
             int M, int N, int K) {
    __shared__ float As[GT_K][GT_M + 4];
    __shared__ float Bs[GT_K][GT_N];
    const int tid = threadIdx.x;
    const int bm = blockIdx.y * GT_M;
    const int bn = blockIdx.x * GT_N;
    const int tx = tid & 15;
    const int ty = tid >> 4;

    float acc[8][4];
#pragma unroll
    for (int i = 0; i < 8; ++i)
#pragma unroll
        for (int j = 0; j < 4; ++j) acc[i][j] = 0.f;

    for (int kt = 0; kt < K; kt += GT_K) {
#pragma unroll
        for (int i = 0; i < 8; ++i) {
            int idx = i * 256 + tid;
            int m = idx >> 4, k = idx & 15;
            int gk = kt + k;
            As[k][m] = (gk < K) ? X[(size_t)(bm + m) * K + gk] : 0.f;
        }
#pragma unroll
        for (int i = 0; i < 4; ++i) {
            int idx = i * 256 + tid;
            int k = idx >> 6, n = idx & 63;
            int gk = kt + k;
            Bs[k][n] = (gk < K) ? W[(size_t)gk * N + bn + n] : 0.f;
        }
        __syncthreads();
#pragma unroll
        for (int k = 0; k < GT_K; ++k) {
            float a[8], b[4];
            const float4 a0 = *(const float4*)&As[k][ty * 8];
            const float4 a1 = *(const float4*)&As[k][ty * 8 + 4];
            const float4 bv = *(const float4*)&Bs[k][tx * 4];
            a[0]=a0.x; a[1]=a0.y; a[2]=a0.z; a[3]=a0.w;
            a[4]=a1.x; a[5]=a1.y; a[6]=a1.z; a[7]=a1.w;
            b[0]=bv.x; b[1]=bv.y; b[2]=bv.z; b[3]=bv.w;
#pragma unroll
            for (int i = 0; i < 8; ++i)
#pragma unroll
                for (int j = 0; j < 4; ++j) acc[i][j] += a[i] * b[j];
        }
        __syncthreads();
    }
    const int n0 = bn + tx * 4;
#pragma unroll
    for (int i = 0; i < 8; ++i) {
        int m = bm + ty * 8 + i;
        float4 v;
        v.x = acc[i][0] + bias[n0 + 0];
        v.y = acc[i][1] + bias[n0 + 1];
        v.z = acc[i][2] + bias[n0 + 2];
        v.w = acc[i][3] + bias[n0 + 3];
        stvec4(&G[(size_t)m * N + n0], v);
    }
}

// ---------------------------------------------------------------------------
// Kernel 2: persistent recurrence. 256 blocks x 1024 threads, 1 row/block,
// 1 block/CU (launch_bounds 1024,4 -> VGPR cap 128, no spill).
// fp16 row-major weights, simple direct-load loops (R5-proven), lgkm barriers.
// ---------------------------------------------------------------------------
__global__ __launch_bounds__(1024, 4)
void marn_rec(const float* __restrict__ G0, const __half* __restrict__ G1h,
              const __half* __restrict__ G2h,
              const __half* __restrict__ hU0, const __half* __restrict__ hV0,
              const __half* __restrict__ hU1, const __half* __restrict__ hV1,
              const __half* __restrict__ hU2, const __half* __restrict__ hV2,
              const __half* __restrict__ haw1, const float* __restrict__ ab1,
              const __half* __restrict__ haw2, const float* __restrict__ ab2,
              const __half* __restrict__ hcw10, const float* __restrict__ cb10,
              const float* __restrict__ cw20, const float* __restrict__ cb20,
              const __half* __restrict__ hcw11, const float* __restrict__ cb11,
              const float* __restrict__ cw21, const float* __restrict__ cb21,
              const __half* __restrict__ hcw12, const float* __restrict__ cb12,
              const float* __restrict__ cw22, const float* __restrict__ cb22,
              const float* __restrict__ fw1, const float* __restrict__ fb1,
              const float* __restrict__ fw2, const float* __restrict__ fb2,
              float* __restrict__ out) {
    __shared__ float hz[256];     // [h0(128)|h1(32)|h2(32)|z(64)]
    __shared__ float cst[192];
    __shared__ float a1s[256];
    __shared__ float attE[768];
    __shared__ float hid[128];
    __shared__ float denomP[12];  // per-wave softmax partials (3 waves/head)
    __shared__ float scratch[7680];
    __shared__ float c2w[3072];   // cw20(2048)|cw21(512)|cw22(512)

    const int tid = threadIdx.x;
    const int row = blockIdx.x;

    if (tid < 256) hz[tid] = 0.f;
    else if (tid < 448) cst[tid - 256] = 0.f;
    for (int i = tid; i < 2048; i += 1024) c2w[i] = cw20[i];
    if (tid < 512) c2w[2048 + tid] = cw21[tid];
    else c2w[2560 + (tid - 512)] = cw22[tid - 512];
    __syncthreads();

    // ---- stage A mapping (960 active): 16-k chunks ----
    const __half* WBa = nullptr; int HOa = 0, STRa = 0, SOa = 0;
    if (tid < 768) {
        const int g = tid & 63, kc = tid >> 6;       // 64 groups x 8 cols, kc 0..11
        const int cb = g * 8;
        if (kc < 8) { WBa = hU0 + (size_t)(16 * kc) * 512 + cb; HOa = 16 * kc; }
        else        { WBa = hV0 + (size_t)(16 * (kc - 8)) * 512 + cb; HOa = 192 + 16 * (kc - 8); }
        STRa = 512;
        SOa = kc * 512 + cb;
    } else if (tid < 960) {
        const int u = tid - 768;                      // 0..191
        const int cell = u / 96, v = u - cell * 96;   // 96 threads/cell
        const int g = v & 15, kc = v >> 4;            // 16 groups x 8 cols, kc 0..5
        const int cb = g * 8;
        const __half* Uc = cell ? hU2 : hU1;
        const __half* Vc = cell ? hV2 : hV1;
        if (kc < 2) { WBa = Uc + (size_t)(16 * kc) * 128 + cb; HOa = 128 + 32 * cell + 16 * kc; }
        else        { WBa = Vc + (size_t)(16 * (kc - 2)) * 128 + cb; HOa = 192 + 16 * (kc - 2); }
        STRa = 128;
        SOa = 6144 + kc * 256 + cell * 128 + cb;
    }
    // ---- att1 mapping (512 active): 12-k chunks ----
    const __half* WB1 = nullptr; int HO1 = 0, SO1 = 0;
    if (tid < 512) {
        const int g = tid & 31, kc = tid >> 5;       // 32 groups x 8 cols, kc 0..15
        const int cb = g * 8;
        WB1 = haw1 + (size_t)(12 * kc) * 256 + cb;
        HO1 = 12 * kc;
        SO1 = kc * 256 + cb;
    }
    // ---- att2 mapping (768 active): 32-k chunks ----
    const int kc2 = tid / 96;                        // 0..7 for tid<768
    const int g2a = tid - kc2 * 96;
    const __half* WB2 = haw2 + (size_t)(32 * (kc2 & 7)) * 768 + g2a * 8;
    const int HO2 = 32 * (kc2 & 7);
    const int SO2 = (kc2 & 7) * 768 + g2a * 8;
    // ---- comp1 mapping (192 active), att_out fused ----
    const __half* WBc = nullptr; int HOc = 0, SOc = 0, KNc = 0, KLc = 0, HSELo = 0, HSELm = 0;
    if (tid < 128) {
        const int g = tid & 7, kc = tid >> 3;        // 8 groups, kc 0..15, 32k
        WBc = hcw10 + (size_t)(32 * kc) * 64 + g * 8;
        HOc = 32 * kc;
        SOc = kc * 64 + g * 8;
        KNc = 64; KLc = 32;
        HSELo = 0; HSELm = 127;
    } else if (tid < 192) {
        const int u = tid - 128;                      // 0..63
        const int cell = u >> 5;
        const int rem = u & 31;
        const int g = rem & 3, kc = rem >> 2;         // 4 groups, kc 0..7, 16k
        WBc = (cell ? hcw12 : hcw11) + (size_t)(16 * kc) * 32 + g * 8;
        HOc = 512 + 128 * cell + 16 * kc;
        SOc = 1024 + cell * 256 + kc * 32 + g * 8;
        KNc = 32; KLc = 16;
        HSELo = 128 + 32 * cell; HSELm = 31;
    }
    const int AHc = HOc / 192;
    const int HBc = (tid < 128) ? 0 : (512 + 128 * (((tid - 128) >> 5) & 1));
    // ---- gates / G-prefetch mapping (192 active) ----
    const int g12_cell = ((tid - 128) >> 5) & 1;
    const int g12_uu   = (tid - 128) & 31;

    float  g0p[4];
    __half g12p[4];
    if (tid < 128) {
        const float* gp = G0 + ((size_t)row * TT + 0) * 512;
#pragma unroll
        for (int q = 0; q < 4; ++q) g0p[q] = gp[q * 128 + tid];
    } else if (tid < 192) {
        const __half* gp = (g12_cell ? G2h : G1h) + ((size_t)row * TT + 0) * 128;
#pragma unroll
        for (int q = 0; q < 4; ++q) g12p[q] = gp[q * 32 + g12_uu];
    }

    for (int t = 0; t < TT; ++t) {
        // ======== stage A compute (16-k chunks) ========
        if (tid < 960) {
            float acc[8];
#pragma unroll
            for (int j = 0; j < 8; ++j) acc[j] = 0.f;
#pragma unroll 16
            for (int k = 0; k < 16; ++k) {
                const float4 wv = *(const float4*)(WBa + (size_t)k * STRa);
                const __half* hw = (const __half*)&wv;
                const float a0 = hz[HOa + k];
#pragma unroll
                for (int j = 0; j < 8; ++j) acc[j] += __half2float(hw[j]) * a0;
            }
            float* s0 = &scratch[SOa];
            *(float4*)s0       = make_float4(acc[0], acc[1], acc[2], acc[3]);
            *(float4*)(s0 + 4) = make_float4(acc[4], acc[5], acc[6], acc[7]);
        }
        BAR();
        // ======== gates (+ G prefetch for t+1) ========
        if (tid < 128) {
            float s[4];
#pragma unroll
            for (int q = 0; q < 4; ++q) {
                const int c4 = q * 128 + tid;
                float v = g0p[q];
#pragma unroll
                for (int kc = 0; kc < 12; ++kc) v += scratch[kc * 512 + c4];
                s[q] = v;
            }
            const float f  = sigf(s[0]);
            const float ig = sigf(s[1]);
            const float o  = sigf(s[2]);
            const float ch = tanhf(s[3]);
            const float c = f * cst[tid] + ig * ch;
            cst[tid] = c;
            hz[tid] = tanhf(c) * o;
            const int tn = (t + 1 < TT) ? t + 1 : TT - 1;
            const float* gp = G0 + ((size_t)row * TT + tn) * 512;
#pragma unroll
            for (int q = 0; q < 4; ++q) g0p[q] = gp[q * 128 + tid];
        } else if (tid < 192) {
            const int cell = g12_cell, uu = g12_uu;
            float s[4];
#pragma unroll
            for (int q = 0; q < 4; ++q) {
                float v = __half2float(g12p[q]);
#pragma unroll
                for (int kc = 0; kc < 6; ++kc)
                    v += scratch[6144 + kc * 256 + cell * 128 + q * 32 + uu];
                s[q] = v;
            }
            const float f  = sigf(s[0]);
            const float ig = sigf(s[1]);
            const float o  = sigf(s[2]);
            const float ch = tanhf(s[3]);
            const int si = 128 + 32 * cell + uu;
            const float c = f * cst[si] + ig * ch;
            cst[si] = c;
            hz[si] = tanhf(c) * o;
            const int tn = (t + 1 < TT) ? t + 1 : TT - 1;
            const __half* gp = (cell ? G2h : G1h) + ((size_t)row * TT + tn) * 128;
#pragma unroll
            for (int q = 0; q < 4; ++q) g12p[q] = gp[q * 32 + uu];
        }
        BAR();
        // ======== att1 compute (12-k chunks) ========
        if (tid < 512) {
            float acc[8];
#pragma unroll
            for (int j = 0; j < 8; ++j) acc[j] = 0.f;
#pragma unroll 12
            for (int k = 0; k < 12; ++k) {
                const float4 wv = *(const float4*)(WB1 + (size_t)k * 256);
                const __half* hw = (const __half*)&wv;
                const float a0 = hz[HO1 + k];
#pragma unroll
                for (int j = 0; j < 8; ++j) acc[j] += __half2float(hw[j]) * a0;
            }
            float* s0 = &scratch[SO1];
            *(float4*)s0       = make_float4(acc[0], acc[1], acc[2], acc[3]);
            *(float4*)(s0 + 4) = make_float4(acc[4], acc[5], acc[6], acc[7]);
        }
        BAR();
        // ======== att1 reduce + relu ========
        if (tid < 256) {
            float s = ab1[tid];
#pragma unroll
            for (int kc = 0; kc < 16; ++kc) s += scratch[kc * 256 + tid];
            a1s[tid] = fmaxf(s, 0.f);
        }
        BAR();
        // ======== att2 compute (32-k chunks) ========
        if (tid < 768) {
            float acc[8];
#pragma unroll
            for (int j = 0; j < 8; ++j) acc[j] = 0.f;
#pragma unroll 16
            for (int k = 0; k < 32; ++k) {
                const float4 wv = *(const float4*)(WB2 + (size_t)k * 768);
                const __half* hw = (const __half*)&wv;
                const float a0 = a1s[HO2 + k];
#pragma unroll
                for (int j = 0; j < 8; ++j) acc[j] += __half2float(hw[j]) * a0;
            }
            float* s0 = &scratch[SO2];
            *(float4*)s0       = make_float4(acc[0], acc[1], acc[2], acc[3]);
            *(float4*)(s0 + 4) = make_float4(acc[4], acc[5], acc[6], acc[7]);
        }
        BAR();
        // ======== att2 reduce + sigmoid + exp + per-wave denom partials ====
        if (tid < 768) {
            float s = ab2[tid];
#pragma unroll
            for (int kc = 0; kc < 8; ++kc) s += scratch[kc * 768 + tid];
            const float e = expf(sigf(s));
            attE[tid] = e;
            // 12 waves cover 768 idx; head boundaries (192) align with 3-wave groups
            float v = e;
#pragma unroll
            for (int sh = 32; sh >= 1; sh >>= 1) v += __shfl_xor(v, sh);
            if ((tid & 63) == 0) denomP[tid >> 6] = v;
        }
        BAR();
        // ======== comp1 compute (att_out + rinv fused) ========
        if (tid < 192) {
            const float ri = 1.f / (denomP[3 * AHc] + denomP[3 * AHc + 1] + denomP[3 * AHc + 2]);
            float acc[8];
#pragma unroll
            for (int j = 0; j < 8; ++j) acc[j] = 0.f;
#pragma unroll 16
            for (int k = 0; k < KLc; ++k) {
                const int idx = HOc + k;
                const float4 wv = *(const float4*)(WBc + (size_t)k * KNc);
                const __half* hw = (const __half*)&wv;
                const float a0 = attE[idx] * ri * hz[HSELo + ((idx - HBc) & HSELm)];
#pragma unroll
                for (int j = 0; j < 8; ++j) acc[j] += __half2float(hw[j]) * a0;
            }
            float* s0 = &scratch[SOc];
            *(float4*)s0       = make_float4(acc[0], acc[1], acc[2], acc[3]);
            *(float4*)(s0 + 4) = make_float4(acc[4], acc[5], acc[6], acc[7]);
        }
        BAR();
        // ======== comp1 reduce + relu ========
        if (tid < 128) {
            float s;
            if (tid < 64) {
                s = cb10[tid];
#pragma unroll
                for (int kc = 0; kc < 16; ++kc) s += scratch[kc * 64 + tid];
            } else {
                const int cc = tid - 64;
                const int cell = cc >> 5, j = cc & 31;
                s = (cell ? cb12 : cb11)[j];
#pragma unroll
                for (int kc = 0; kc < 8; ++kc)
                    s += scratch[1024 + cell * 256 + kc * 32 + j];
            }
            hid[tid] = fmaxf(s, 0.f);
        }
        BAR();
        // ======== comp2 + z softmax (one wave) ========
        if (tid < 64) {
            const int j = tid;
            float acc;
            if (j < 32) {
                acc = cb20[j];
#pragma unroll
                for (int k = 0; k < 64; ++k) acc += hid[k] * c2w[k * 32 + j];
            } else if (j < 48) {
                const int o = j - 32; acc = cb21[o];
#pragma unroll
                for (int k = 0; k < 32; ++k) acc += hid[64 + k] * c2w[2048 + k * 16 + o];
            } else {
                const int o = j - 48; acc = cb22[o];
#pragma unroll
                for (int k = 0; k < 32; ++k) acc += hid[96 + k] * c2w[2560 + k * 16 + o];
            }
            const float e = expf(sigf(acc));
            float v = e;
#pragma unroll
            for (int s = 32; s >= 1; s >>= 1) v += __shfl_xor(v, s);
            hz[192 + j] = e / v;
        }
        BAR();
    }

    __syncthreads();
    // ======== final MLP ========
    if (tid < 64) {
        const int j = tid;
        float acc = fb1[j];
#pragma unroll 8
        for (int k = 0; k < 64; ++k)  acc += hz[192 + k] * fw1[k * 64 + j];
#pragma unroll 8
        for (int k = 0; k < 192; ++k) acc += hz[k] * fw1[(64 + k) * 64 + j];
        hid[j] = fmaxf(acc, 0.f);
    }
    __syncthreads();
    if (tid < 64) {
        float v = hid[tid] * fw2[tid];
#pragma unroll
        for (int s = 32; s >= 1; s >>= 1) v += __shfl_xor(v, s);
        if (tid == 0) out[row] = v + fb2[0];
    }
}

// ---------------------------------------------------------------------------
extern "C" void kernel_launch(void* const* d_in, const int* in_sizes, int n_in,
                              void* d_out, int out_size, void* d_ws, size_t ws_size,
                              hipStream_t stream) {
    const float* x0   = (const float*)d_in[0];
    const float* x1   = (const float*)d_in[1];
    const float* x2   = (const float*)d_in[2];
    const float* W0   = (const float*)d_in[3];
    const float* U0   = (const float*)d_in[4];
    const float* V0   = (const float*)d_in[5];
    const float* b0   = (const float*)d_in[6];
    const float* W1   = (const float*)d_in[7];
    const float* U1   = (const float*)d_in[8];
    const float* V1   = (const float*)d_in[9];
    const float* b1   = (const float*)d_in[10];
    const float* W2   = (const float*)d_in[11];
    const float* U2   = (const float*)d_in[12];
    const float* V2   = (const float*)d_in[13];
    const float* b2   = (const float*)d_in[14];
    const float* aw1  = (const float*)d_in[15];
    const float* ab1  = (const float*)d_in[16];
    const float* aw2  = (const float*)d_in[17];
    const float* ab2  = (const float*)d_in[18];
    const float* cw10 = (const float*)d_in[19];
    const float* cb10 = (const float*)d_in[20];
    const float* cw20 = (const float*)d_in[21];
    const float* cb20 = (const float*)d_in[22];
    const float* cw11 = (const float*)d_in[23];
    const float* cb11 = (const float*)d_in[24];
    const float* cw21 = (const float*)d_in[25];
    const float* cb21 = (const float*)d_in[26];
    const float* cw12 = (const float*)d_in[27];
    const float* cb12 = (const float*)d_in[28];
    const float* cw22 = (const float*)d_in[29];
    const float* cb22 = (const float*)d_in[30];
    const float* fw1  = (const float*)d_in[31];
    const float* fb1  = (const float*)d_in[32];
    const float* fw2  = (const float*)d_in[33];
    const float* fb2  = (const float*)d_in[34];
    float* out = (float*)d_out;

    const size_t M = (size_t)BB * TT;   // 65536

    float*  G0  = (float*)d_ws;                 // M*512 f32
    __half* G1h = (__half*)(G0 + M * 512);      // M*128 f16
    __half* G2h = G1h + M * 128;                // M*128 f16
    __half* hU0   = G2h + M * 128;
    __half* hV0   = hU0 + 65536;
    __half* hU1   = hV0 + 32768;
    __half* hV1   = hU1 + 4096;
    __half* hU2   = hV1 + 8192;
    __half* hV2   = hU2 + 4096;
    __half* haw1  = hV2 + 8192;
    __half* haw2  = haw1 + 49152;
    __half* hcw10 = haw2 + 196608;
    __half* hcw11 = hcw10 + 32768;
    __half* hcw12 = hcw11 + 4096;

    f2h<<<(65536 + 255) / 256, 256, 0, stream>>>(U0, hU0, 65536);
    f2h<<<(32768 + 255) / 256, 256, 0, stream>>>(V0, hV0, 32768);
    f2h<<<(4096 + 255) / 256, 256, 0, stream>>>(U1, hU1, 4096);
    f2h<<<(8192 + 255) / 256, 256, 0, stream>>>(V1, hV1, 8192);
    f2h<<<(4096 + 255) / 256, 256, 0, stream>>>(U2, hU2, 4096);
    f2h<<<(8192 + 255) / 256, 256, 0, stream>>>(V2, hV2, 8192);
    f2h<<<(49152 + 255) / 256, 256, 0, stream>>>(aw1, haw1, 49152);
    f2h<<<(196608 + 255) / 256, 256, 0, stream>>>(aw2, haw2, 196608);
    f2h<<<(32768 + 255) / 256, 256, 0, stream>>>(cw10, hcw10, 32768);
    f2h<<<(4096 + 255) / 256, 256, 0, stream>>>(cw11, hcw11, 4096);
    f2h<<<(4096 + 255) / 256, 256, 0, stream>>>(cw12, hcw12, 4096);

    xw_gemm<float><<<dim3(512 / GT_N, M / GT_M), 256, 0, stream>>>(x0, W0, b0, G0, (int)M, 512, 300);
    xw_gemm<__half><<<dim3(128 / GT_N, M / GT_M), 256, 0, stream>>>(x1, W1, b1, G1h, (int)M, 128, 74);
    xw_gemm<__half><<<dim3(128 / GT_N, M / GT_M), 256, 0, stream>>>(x2, W2, b2, G2h, (int)M, 128, 35);

    // 256 blocks x 1024 threads, 1 row/block, 1 block/CU
    marn_rec<<<256, 1024, 0, stream>>>(G0, G1h, G2h, hU0, hV0, hU1, hV1, hU2, hV2,
                                       haw1, ab1, haw2, ab2,
                                       hcw10, cb10, cw20, cb20,
                                       hcw11, cb11, cw21, cb21,
                                       hcw12, cb12, cw22, cb22,
                                       fw1, fb1, fw2, fb2, out);
}